// Round 8
// baseline (110.111 us; speedup 1.0000x reference)
//
#include <hip/hip_runtime.h>

typedef __attribute__((ext_vector_type(4)))  float f32x4;
typedef __attribute__((ext_vector_type(16))) float f32x16;
typedef __attribute__((ext_vector_type(8)))  short s16x8;

#define KK 9
#define NCHUNK 23       // tier-2 fallback chunk count

__device__ inline unsigned short f2bf(float f) {
    union { float f; unsigned int u; } v; v.f = f;
    unsigned int u = v.u + 0x7FFFu + ((v.u >> 16) & 1u);   // RNE
    return (unsigned short)(u >> 16);
}

// ===========================================================================
// TIER 1: 32x32x16 MFMA, columns = (n, p), wave = 2 adjacent y-groups.
// A-row windows of groups (g, g+1) overlap 8/12 -> 16 ds_reads feed 24 MFMAs.
// ===========================================================================

// Bg[( (chunk*64 + lane)*8 + e )]:
//   chunk = kx*12 + s  (kx 0..8, s 0..11, ky' = s-3)
//   lane: col = lane&31 = n + 8p ; khalf = lane>>5
//   k = khalf*8 + e -> cp ; dc = 15-cp ; ky = (s-3)+p
//   val = wgt[n, dc, ky, kx] if 0<=ky<=8 else 0
__global__ void prep_w32(const float* __restrict__ wgt, unsigned short* __restrict__ Bg) {
    int idx = blockIdx.x * 256 + threadIdx.x;
    if (idx >= 108 * 64 * 8) return;
    int e     = idx & 7;
    int lanei = (idx >> 3) & 63;
    int chunk = idx >> 9;
    int col   = lanei & 31;
    int khalf = lanei >> 5;
    int n  = col & 7;
    int p  = col >> 3;
    int kx = chunk / 12;
    int s  = chunk - 12 * kx;
    int ky = s - 3 + p;
    int cp = khalf * 8 + e;
    int dc = 15 - cp;
    float val = 0.f;
    if (ky >= 0 && ky <= 8)
        val = wgt[((n * 16 + dc) * KK + ky) * KK + kx];
    Bg[idx] = f2bf(val);
}

// 512 threads = 8 waves.  wave = (pair pr = wave&3, tile t = wave>>2).
// Wave computes y-groups 2pr and 2pr+1 of tile t.  Per kx: batch-load 12 B
// fragments, then 16 unrolled row-steps {1 ds_read_b128 + 1-2 MFMA}.
__global__ __launch_bounds__(512, 4) void fconv_mfma32(
    const float* __restrict__ x,
    const unsigned short* __restrict__ Bg,
    float* __restrict__ out)
{
    __shared__ char smb[65536];   // [tile][half][cell=y*32+w][8ch] bf16

    const int tid = threadIdx.x;
    // XCD-aware bijective swizzle (512 blocks, 8 XCDs): co-locate all 16 jp
    // of 4 consecutive b on one XCD -> per-XCD x working set 2 MB < 4 MB L2.
    const int wg  = ((blockIdx.x & 7) << 6) + (blockIdx.x >> 3);
    const int b   = wg >> 4;
    const int jp  = wg & 15;      // j0 = jp, j1 = jp + 16

    // ---- stage two x tiles: 16 channels each (4j-15 .. 4j) ----
    const float* xb = x + ((size_t)b << 17);
    #pragma unroll
    for (int t = 0; t < 2; ++t) {
        const int j = jp + t * 16;
        int choff[16];
        #pragma unroll
        for (int i = 0; i < 16; ++i)
            choff[i] = ((4 * j - 15 + i) & 127) << 10;   // uniform -> SGPR

        #pragma unroll
        for (int i = 0; i < 2; ++i) {
            int cell = i * 512 + tid;
            #pragma unroll
            for (int h = 0; h < 2; ++h) {
                union { unsigned short u16[8]; uint4 v; } pk;
                #pragma unroll
                for (int e = 0; e < 8; ++e)
                    pk.u16[e] = f2bf(xb[choff[h * 8 + e] + cell]);
                *(uint4*)(smb + t * 32768 + h * 16384 + cell * 16) = pk.v;
            }
        }
    }
    __syncthreads();

    const int lane  = tid & 63;
    const int wave  = tid >> 6;
    const int pr    = wave & 3;      // y-group pair: groups 2pr, 2pr+1
    const int t     = wave >> 2;     // j tile
    const int wrow  = lane & 31;     // A row = output w ; D col
    const int khalf = lane >> 5;     // channel half (k-group)
    const int g8    = pr * 8;        // base output row of group 2pr

    f32x16 acc0 = (f32x16)0.f;       // y-group 2pr   (rows g8   .. g8+3)
    f32x16 acc1 = (f32x16)0.f;       // y-group 2pr+1 (rows g8+4 .. g8+7)
    const char* bp    = (const char*)Bg + (lane << 4);
    const char* abuf  = smb + t * 32768 + (khalf << 14);

    #pragma unroll 1
    for (int kx = 0; kx < 9; ++kx) {
        const char* ab  = abuf + (((wrow - kx) & 31) << 4);
        const char* bpk = bp + kx * 12288;

        s16x8 bb[12];
        #pragma unroll
        for (int s = 0; s < 12; ++s)
            bb[s] = *(const s16x8*)(bpk + (s << 10));

        // rows R = g8-8+rr ; acc0 uses s = 11-rr (rr<=11), acc1 s = 15-rr (rr>=4)
        #pragma unroll
        for (int rr = 0; rr < 16; ++rr) {
            int R = (g8 - 8 + rr) & 31;
            s16x8 a = *(const s16x8*)(ab + (R << 9));
            if (rr <= 11)
                acc0 = __builtin_amdgcn_mfma_f32_32x32x16_bf16(a, bb[11 - rr], acc0, 0, 0, 0);
            if (rr >= 4)
                acc1 = __builtin_amdgcn_mfma_f32_32x32x16_bf16(a, bb[15 - rr], acc1, 0, 0, 0);
        }
    }

    // ---- store: D row = (reg&3)+8*(reg>>2)+4*khalf = w ; col = n+8p ----
    const int n  = wrow & 7;
    const int p  = wrow >> 3;
    const int jj = jp + t * 16;
    {
        float* ob = out + (((size_t)(b * 256 + n * 32 + jj)) << 10)
                        + ((g8 + p) << 5) + 4 * khalf;
        #pragma unroll
        for (int q = 0; q < 4; ++q) {
            f32x4 v = { acc0[4*q], acc0[4*q+1], acc0[4*q+2], acc0[4*q+3] };
            *(f32x4*)(ob + q * 8) = v;
        }
    }
    {
        float* ob = out + (((size_t)(b * 256 + n * 32 + jj)) << 10)
                        + ((g8 + 4 + p) << 5) + 4 * khalf;
        #pragma unroll
        for (int q = 0; q < 4; ++q) {
            f32x4 v = { acc1[4*q], acc1[4*q+1], acc1[4*q+2], acc1[4*q+3] };
            *(f32x4*)(ob + q * 8) = v;
        }
    }
}

// ===========================================================================
// TIER 2: 16x16x32 ky-paired kernel (proven; needs only 23 KB ws).
// ===========================================================================
__global__ void prep_w(const float* __restrict__ wgt, unsigned short* __restrict__ Bg) {
    int idx = blockIdx.x * 256 + threadIdx.x;
    if (idx >= NCHUNK * 4 * 16 * 8) return;
    int e   = idx & 7;
    int col = (idx >> 3) & 15;
    int g   = (idx >> 7) & 3;
    int c   = idx >> 9;
    int pi   = g >> 1;
    int half = g & 1;
    int cp = half * 8 + e;
    int dc = 15 - cp;
    int q  = 2 * c + pi;
    int n  = col & 7;
    int t  = col >> 3;
    float val = 0.f;
    if (q <= 44) {
        int ky2 = q / 9;
        int kx  = q - 9 * ky2;
        int ky  = 2 * ky2 + t;
        if (ky <= 8)
            val = wgt[((n * 16 + dc) * KK + ky) * KK + kx];
    }
    Bg[idx] = f2bf(val);
}

__global__ __launch_bounds__(256) void fconv_mfma(
    const float* __restrict__ x,
    const unsigned short* __restrict__ Bg,
    float* __restrict__ out)
{
    __shared__ char smem[32768 + 4096];
    char*  smb     = smem;
    float* handoff = (float*)(smem + 32768);

    const int tid = threadIdx.x;
    const int b   = blockIdx.x >> 5;
    const int j   = blockIdx.x & 31;

    const float* xb = x + ((size_t)b << 17);
    int choff[16];
    #pragma unroll
    for (int i = 0; i < 16; ++i)
        choff[i] = ((4 * j - 15 + i) & 127) << 10;

    #pragma unroll
    for (int i = 0; i < 4; ++i) {
        int cell = i * 256 + tid;
        #pragma unroll
        for (int h = 0; h < 2; ++h) {
            union { unsigned short u16[8]; uint4 v; } pk;
            #pragma unroll
            for (int e = 0; e < 8; ++e)
                pk.u16[e] = f2bf(xb[choff[h * 8 + e] + cell]);
            *(uint4*)(smb + h * 16384 + cell * 16) = pk.v;
        }
    }
    __syncthreads();

    const int lane = tid & 63;
    const int wave = tid >> 6;
    const int r    = lane & 15;
    const int g    = lane >> 4;
    const int half = g & 1;
    const int pi   = g >> 1;
    const int y0   = wave * 8;

    f32x4 acc[8][2];
    #pragma unroll
    for (int dy = 0; dy < 8; ++dy) { acc[dy][0] = (f32x4)0.f; acc[dy][1] = (f32x4)0.f; }

    const char* bptr = (const char*)Bg + ((g * 16 + r) << 4);
    s16x8 bfrag = *(const s16x8*)(bptr);

    #pragma unroll 1
    for (int c = 0; c < NCHUNK; ++c) {
        int q   = 2 * c + pi;
        int ky2 = q / 9;
        int kx  = q - 9 * ky2;
        int wr  = (r - kx) & 31;
        int yb  = (y0 - 2 * ky2) & 31;
        int abase = (half << 14) + (wr << 4);

        int cn = (c < NCHUNK - 1) ? c + 1 : NCHUNK - 1;
        s16x8 bnext = *(const s16x8*)(bptr + (cn << 10));

        #pragma unroll
        for (int dy = 0; dy < 8; ++dy) {
            int yy = (yb + dy) & 31;
            int ra = abase + (yy << 9);
            s16x8 a0 = *(const s16x8*)(smb + ra);
            s16x8 a1 = *(const s16x8*)(smb + (ra ^ 256));
            acc[dy][0] = __builtin_amdgcn_mfma_f32_16x16x32_bf16(a0, bfrag, acc[dy][0], 0, 0, 0);
            acc[dy][1] = __builtin_amdgcn_mfma_f32_16x16x32_bf16(a1, bfrag, acc[dy][1], 0, 0, 0);
        }
        bfrag = bnext;
    }

    float recv[8][2][4];
    #pragma unroll
    for (int dy = 0; dy < 8; ++dy)
        #pragma unroll
        for (int h = 0; h < 2; ++h)
            #pragma unroll
            for (int i = 0; i < 4; ++i)
                recv[dy][h][i] = __shfl_xor(acc[dy][h][i], 8);

    if (r < 8) {
        #pragma unroll
        for (int h = 0; h < 2; ++h)
            *(f32x4*)&handoff[wave * 256 + r * 32 + h * 16 + g * 4] = *(f32x4*)recv[7][h];
    }
    __syncthreads();

    if (r < 8) {
        const int pw = (wave + 3) & 3;
        f32x4 prev[2];
        #pragma unroll
        for (int h = 0; h < 2; ++h)
            prev[h] = *(f32x4*)&handoff[pw * 256 + r * 32 + h * 16 + g * 4];

        float* ob = out + (((size_t)(b * 256 + r * 32 + j)) << 10) + (g << 2);
        #pragma unroll
        for (int dy = 0; dy < 8; ++dy) {
            #pragma unroll
            for (int h = 0; h < 2; ++h) {
                f32x4 t1 = (dy == 0) ? prev[h] : *(f32x4*)recv[dy - 1][h];
                f32x4 v  = acc[dy][h] + t1;
                *(f32x4*)(ob + (y0 + dy) * 32 + h * 16) = v;
            }
        }
    }
}

// ===========================================================================
// TIER 3: fp32 VALU fallback (no workspace needed).
// ===========================================================================
__global__ __launch_bounds__(256, 2) void fconv_fallback(
    const float* __restrict__ x,
    const float* __restrict__ wgt,
    float* __restrict__ out)
{
    __shared__ float sw[16 * KK * KK * 8];
    const int tid = threadIdx.x;
    for (int idx = tid; idx < 8 * 16 * KK * KK; idx += 256) {
        int n  = idx / (16 * KK * KK);
        int rm = idx - n * (16 * KK * KK);
        int dc = rm / (KK * KK);
        int r2 = rm - dc * (KK * KK);
        int ky = r2 / KK;
        int kx = r2 - ky * KK;
        sw[((dc * KK + kx) * KK + ky) * 8 + n] = wgt[idx];
    }
    __syncthreads();

    const int bid = blockIdx.x;
    const int b   = bid >> 6;
    const int j   = (bid >> 1) & 31;
    const int yh  = bid & 1;
    const int xw  = tid & 31;
    const int yg  = tid >> 5;
    const int y_base = yh * 16 + yg * 2;

    int rows[10];
    #pragma unroll
    for (int i = 0; i < 10; ++i)
        rows[i] = ((y_base + 24 + i) & 31) << 5;

    float acc[8][2];
    #pragma unroll
    for (int n = 0; n < 8; ++n) { acc[n][0] = 0.f; acc[n][1] = 0.f; }

    const int c0 = 4 * j;
    #pragma unroll 1
    for (int dc = 0; dc < 16; ++dc) {
        const int c_src = (c0 - dc) & 127;
        const float* bx = x + (((size_t)b * 128 + c_src) << 10);
        #pragma unroll 1
        for (int kx = 0; kx < KK; ++kx) {
            const int x_col = (xw - kx) & 31;
            float win[10];
            #pragma unroll
            for (int i = 0; i < 10; ++i)
                win[i] = bx[rows[i] + x_col];
            const float4* wp = (const float4*)&sw[((dc * KK + kx) * KK) * 8];
            #pragma unroll
            for (int ky = 0; ky < KK; ++ky) {
                float4 wA = wp[2 * ky];
                float4 wB = wp[2 * ky + 1];
                float x0 = win[8 - ky];
                float x1 = win[9 - ky];
                acc[0][0] += x0 * wA.x; acc[0][1] += x1 * wA.x;
                acc[1][0] += x0 * wA.y; acc[1][1] += x1 * wA.y;
                acc[2][0] += x0 * wA.z; acc[2][1] += x1 * wA.z;
                acc[3][0] += x0 * wA.w; acc[3][1] += x1 * wA.w;
                acc[4][0] += x0 * wB.x; acc[4][1] += x1 * wB.x;
                acc[5][0] += x0 * wB.y; acc[5][1] += x1 * wB.y;
                acc[6][0] += x0 * wB.z; acc[6][1] += x1 * wB.z;
                acc[7][0] += x0 * wB.w; acc[7][1] += x1 * wB.w;
            }
        }
    }
    #pragma unroll
    for (int n = 0; n < 8; ++n) {
        float* op = out + ((((size_t)b * 256) + n * 32 + j) << 10) + (y_base << 5) + xw;
        op[0]  = acc[n][0];
        op[32] = acc[n][1];
    }
}

extern "C" void kernel_launch(void* const* d_in, const int* in_sizes, int n_in,
                              void* d_out, int out_size, void* d_ws, size_t ws_size,
                              hipStream_t stream) {
    const float* x   = (const float*)d_in[0];
    const float* w   = (const float*)d_in[1];
    float*       out = (float*)d_out;

    const size_t BG32_BYTES = (size_t)108 * 64 * 8 * sizeof(unsigned short);  // 110592
    const size_t BG16_BYTES = (size_t)NCHUNK * 4 * 16 * 8 * sizeof(unsigned short);

    if (ws_size >= BG32_BYTES) {
        unsigned short* Bg = (unsigned short*)d_ws;
        prep_w32<<<216, 256, 0, stream>>>(w, Bg);
        fconv_mfma32<<<512, 512, 0, stream>>>(x, Bg, out);
    } else if (ws_size >= BG16_BYTES) {
        unsigned short* Bg = (unsigned short*)d_ws;
        prep_w<<<46, 256, 0, stream>>>(w, Bg);
        fconv_mfma<<<1024, 256, 0, stream>>>(x, Bg, out);
    } else {
        fconv_fallback<<<2048, 256, 0, stream>>>(x, w, out);
    }
}

// Round 10
// 100.176 us; speedup vs baseline: 1.0992x; 1.0992x over previous
//
#include <hip/hip_runtime.h>
#include <hip/hip_bf16.h>

typedef __attribute__((ext_vector_type(4)))  float f32x4;
typedef __attribute__((ext_vector_type(16))) float f32x16;
typedef __attribute__((ext_vector_type(8)))  short s16x8;

#define KK 9
#define NCHUNK 23       // tier-2 fallback chunk count

__device__ inline unsigned short f2bf(float f) {
    union { float f; unsigned int u; } v; v.f = f;
    unsigned int u = v.u + 0x7FFFu + ((v.u >> 16) & 1u);   // RNE
    return (unsigned short)(u >> 16);
}

// ===========================================================================
// TIER 1: 32x32x16 MFMA, columns = (n, p), wave = 2 adjacent y-groups,
// explicit 2-phase software pipeline (B reg ping-pong + batched ds_reads).
// ===========================================================================

// Bg[( (chunk*64 + lane)*8 + e )]:
//   chunk = kx*12 + s  (kx 0..8, s 0..11, ky' = s-3)
//   lane: col = lane&31 = n + 8p ; khalf = lane>>5
//   ky = (s-3)+p ; dc = 15 - (khalf*8+e)
//   val = wgt[n, dc, ky, kx] if 0<=ky<=8 else 0
__global__ void prep_w32(const float* __restrict__ wgt, unsigned short* __restrict__ Bg) {
    int idx = blockIdx.x * 256 + threadIdx.x;
    if (idx >= 108 * 64 * 8) return;
    int e     = idx & 7;
    int lanei = (idx >> 3) & 63;
    int chunk = idx >> 9;
    int col   = lanei & 31;
    int khalf = lanei >> 5;
    int n  = col & 7;
    int p  = col >> 3;
    int kx = chunk / 12;
    int s  = chunk - 12 * kx;
    int ky = s - 3 + p;
    int cp = khalf * 8 + e;
    int dc = 15 - cp;
    float val = 0.f;
    if (ky >= 0 && ky <= 8)
        val = wgt[((n * 16 + dc) * KK + ky) * KK + kx];
    Bg[idx] = f2bf(val);
}

// 512 threads = 8 waves.  wave = (pair pr = wave&3, tile t = wave>>2).
// Wave computes y-groups 2pr, 2pr+1 of tile t (output rows 8pr..8pr+7).
// Rows rr 0..15 map to x-rows (8pr-8+rr)&31; acc0 uses s=11-rr (rr<=11),
// acc1 uses s=15-rr (rr>=4).  Phase A = s 6..11 (bbl), phase B = s 0..5 (bbh).
__global__ __launch_bounds__(512, 4) void fconv_mfma32(
    const float* __restrict__ x,
    const unsigned short* __restrict__ Bg,
    float* __restrict__ out)
{
    __shared__ char smb[65536];   // [tile][half][cell=y*32+w][8ch] bf16

    const int tid = threadIdx.x;
    // XCD-aware bijective swizzle (512 blocks = 8 XCDs x 64)
    const int wg  = ((blockIdx.x & 7) << 6) + (blockIdx.x >> 3);
    const int b   = wg >> 4;
    const int jp  = wg & 15;      // j0 = jp, j1 = jp + 16

    // ---- stage two x tiles: float2 loads + cvt_pk_bf16 + v_perm transpose ----
    const float* xb = x + ((size_t)b << 17);
    const int cell = tid * 2;                        // 2 adjacent cells/thread
    #pragma unroll
    for (int tt = 0; tt < 2; ++tt) {
        const int j = jp + tt * 16;
        int choff[16];
        #pragma unroll
        for (int i = 0; i < 16; ++i)
            choff[i] = ((4 * j - 15 + i) & 127) << 10;   // uniform -> SGPR

        #pragma unroll
        for (int h = 0; h < 2; ++h) {
            unsigned int u[8];
            #pragma unroll
            for (int e = 0; e < 8; ++e) {
                float2 v = *(const float2*)(xb + choff[h * 8 + e] + cell);
                union { __hip_bfloat162 h2; unsigned int u32; } cv;
                cv.h2 = __float22bfloat162_rn(v);
                u[e] = cv.u32;      // lo16 = cell, hi16 = cell+1
            }
            uint4 lo, hi;
            lo.x = __builtin_amdgcn_perm(u[1], u[0], 0x05040100u);
            lo.y = __builtin_amdgcn_perm(u[3], u[2], 0x05040100u);
            lo.z = __builtin_amdgcn_perm(u[5], u[4], 0x05040100u);
            lo.w = __builtin_amdgcn_perm(u[7], u[6], 0x05040100u);
            hi.x = __builtin_amdgcn_perm(u[1], u[0], 0x07060302u);
            hi.y = __builtin_amdgcn_perm(u[3], u[2], 0x07060302u);
            hi.z = __builtin_amdgcn_perm(u[5], u[4], 0x07060302u);
            hi.w = __builtin_amdgcn_perm(u[7], u[6], 0x07060302u);
            char* wp = smb + tt * 32768 + h * 16384 + cell * 16;
            *(uint4*)(wp)      = lo;
            *(uint4*)(wp + 16) = hi;
        }
    }
    __syncthreads();

    const int lane  = tid & 63;
    const int wave  = tid >> 6;
    const int pr    = wave & 3;      // y-group pair
    const int t     = wave >> 2;     // j tile
    const int wrow  = lane & 31;     // A row = output w ; D col
    const int khalf = lane >> 5;     // channel half
    const int g8    = pr * 8;

    f32x16 acc0 = (f32x16)0.f;       // rows g8   .. g8+3
    f32x16 acc1 = (f32x16)0.f;       // rows g8+4 .. g8+7
    const char* bp   = (const char*)Bg + (lane << 4);
    const char* abuf = smb + t * 32768 + (khalf << 14);

    #define BLD(dst, kxv, s)  dst = *(const s16x8*)(bp + ((((kxv) * 12 + (s)) << 10)))
    #define ALD(dst, rr)      dst = *(const s16x8*)(ab + (((g8 - 8 + (rr)) & 31) << 9))
    #define M0(a_, b_) acc0 = __builtin_amdgcn_mfma_f32_32x32x16_bf16(a_, b_, acc0, 0, 0, 0)
    #define M1(a_, b_) acc1 = __builtin_amdgcn_mfma_f32_32x32x16_bf16(a_, b_, acc1, 0, 0, 0)

    s16x8 bbl0, bbl1, bbl2, bbl3, bbl4, bbl5;
    s16x8 bbh0, bbh1, bbh2, bbh3, bbh4, bbh5;
    BLD(bbl0, 0, 6);  BLD(bbl1, 0, 7);  BLD(bbl2, 0, 8);
    BLD(bbl3, 0, 9);  BLD(bbl4, 0, 10); BLD(bbl5, 0, 11);

    #pragma unroll 1
    for (int kx = 0; kx < 9; ++kx) {
        const char* ab = abuf + (((wrow - kx) & 31) << 4);
        const int  kxn = (kx < 8) ? kx + 1 : 8;

        // ---------- phase A: consume bbl (s 6..11), prefetch bbh ----------
        BLD(bbh0, kx, 0); BLD(bbh1, kx, 1); BLD(bbh2, kx, 2);
        BLD(bbh3, kx, 3); BLD(bbh4, kx, 4); BLD(bbh5, kx, 5);

        s16x8 a0, a1, a2, a3, a4, a5, ak0, ak1, ak2, ak3;
        ALD(a0, 0); ALD(a1, 1); ALD(a2, 2); ALD(a3, 3);
        __builtin_amdgcn_s_setprio(1);
        M0(a0, bbl5); M0(a1, bbl4);
        ALD(a4, 4); ALD(a5, 5);
        M0(a2, bbl3); M0(a3, bbl2);
        ALD(ak0, 6); ALD(ak1, 7);
        M0(a4, bbl1); M1(a4, bbl5);
        ALD(ak2, 8); ALD(ak3, 9);
        M0(a5, bbl0); M1(a5, bbl4);
        M1(ak0, bbl3); M1(ak1, bbl2); M1(ak2, bbl1); M1(ak3, bbl0);
        __builtin_amdgcn_s_setprio(0);

        // ---------- phase B: consume bbh (s 0..5), prefetch next bbl ----------
        BLD(bbl0, kxn, 6);  BLD(bbl1, kxn, 7);  BLD(bbl2, kxn, 8);
        BLD(bbl3, kxn, 9);  BLD(bbl4, kxn, 10); BLD(bbl5, kxn, 11);

        s16x8 b0, b1, b2, b3, b4, b5;
        ALD(b0, 10); ALD(b1, 11);
        __builtin_amdgcn_s_setprio(1);
        M0(ak0, bbh5); M0(ak1, bbh4);
        ALD(b2, 12); ALD(b3, 13);
        M0(ak2, bbh3); M0(ak3, bbh2);
        ALD(b4, 14); ALD(b5, 15);
        M0(b0, bbh1); M0(b1, bbh0);
        M1(b0, bbh5); M1(b1, bbh4); M1(b2, bbh3);
        M1(b3, bbh2); M1(b4, bbh1); M1(b5, bbh0);
        __builtin_amdgcn_s_setprio(0);
    }
    #undef BLD
    #undef ALD
    #undef M0
    #undef M1

    // ---- store: D row = (reg&3)+8*(reg>>2)+4*khalf = w ; col = n+8p ----
    const int n  = wrow & 7;
    const int p  = wrow >> 3;
    const int jj = jp + t * 16;
    {
        float* ob = out + (((size_t)(b * 256 + n * 32 + jj)) << 10)
                        + ((g8 + p) << 5) + 4 * khalf;
        #pragma unroll
        for (int q = 0; q < 4; ++q) {
            f32x4 v = { acc0[4*q], acc0[4*q+1], acc0[4*q+2], acc0[4*q+3] };
            *(f32x4*)(ob + q * 8) = v;
        }
    }
    {
        float* ob = out + (((size_t)(b * 256 + n * 32 + jj)) << 10)
                        + ((g8 + 4 + p) << 5) + 4 * khalf;
        #pragma unroll
        for (int q = 0; q < 4; ++q) {
            f32x4 v = { acc1[4*q], acc1[4*q+1], acc1[4*q+2], acc1[4*q+3] };
            *(f32x4*)(ob + q * 8) = v;
        }
    }
}

// ===========================================================================
// TIER 2: 16x16x32 ky-paired kernel (proven; needs only 23 KB ws).
// ===========================================================================
__global__ void prep_w(const float* __restrict__ wgt, unsigned short* __restrict__ Bg) {
    int idx = blockIdx.x * 256 + threadIdx.x;
    if (idx >= NCHUNK * 4 * 16 * 8) return;
    int e   = idx & 7;
    int col = (idx >> 3) & 15;
    int g   = (idx >> 7) & 3;
    int c   = idx >> 9;
    int pi   = g >> 1;
    int half = g & 1;
    int cp = half * 8 + e;
    int dc = 15 - cp;
    int q  = 2 * c + pi;
    int n  = col & 7;
    int t  = col >> 3;
    float val = 0.f;
    if (q <= 44) {
        int ky2 = q / 9;
        int kx  = q - 9 * ky2;
        int ky  = 2 * ky2 + t;
        if (ky <= 8)
            val = wgt[((n * 16 + dc) * KK + ky) * KK + kx];
    }
    Bg[idx] = f2bf(val);
}

__global__ __launch_bounds__(256) void fconv_mfma(
    const float* __restrict__ x,
    const unsigned short* __restrict__ Bg,
    float* __restrict__ out)
{
    __shared__ char smem[32768 + 4096];
    char*  smb     = smem;
    float* handoff = (float*)(smem + 32768);

    const int tid = threadIdx.x;
    const int b   = blockIdx.x >> 5;
    const int j   = blockIdx.x & 31;

    const float* xb = x + ((size_t)b << 17);
    int choff[16];
    #pragma unroll
    for (int i = 0; i < 16; ++i)
        choff[i] = ((4 * j - 15 + i) & 127) << 10;

    #pragma unroll
    for (int i = 0; i < 4; ++i) {
        int cell = i * 256 + tid;
        #pragma unroll
        for (int h = 0; h < 2; ++h) {
            union { unsigned short u16[8]; uint4 v; } pk;
            #pragma unroll
            for (int e = 0; e < 8; ++e)
                pk.u16[e] = f2bf(xb[choff[h * 8 + e] + cell]);
            *(uint4*)(smb + h * 16384 + cell * 16) = pk.v;
        }
    }
    __syncthreads();

    const int lane = tid & 63;
    const int wave = tid >> 6;
    const int r    = lane & 15;
    const int g    = lane >> 4;
    const int half = g & 1;
    const int pi   = g >> 1;
    const int y0   = wave * 8;

    f32x4 acc[8][2];
    #pragma unroll
    for (int dy = 0; dy < 8; ++dy) { acc[dy][0] = (f32x4)0.f; acc[dy][1] = (f32x4)0.f; }

    const char* bptr = (const char*)Bg + ((g * 16 + r) << 4);
    s16x8 bfrag = *(const s16x8*)(bptr);

    #pragma unroll 1
    for (int c = 0; c < NCHUNK; ++c) {
        int q   = 2 * c + pi;
        int ky2 = q / 9;
        int kx  = q - 9 * ky2;
        int wr  = (r - kx) & 31;
        int yb  = (y0 - 2 * ky2) & 31;
        int abase = (half << 14) + (wr << 4);

        int cn = (c < NCHUNK - 1) ? c + 1 : NCHUNK - 1;
        s16x8 bnext = *(const s16x8*)(bptr + (cn << 10));

        #pragma unroll
        for (int dy = 0; dy < 8; ++dy) {
            int yy = (yb + dy) & 31;
            int ra = abase + (yy << 9);
            s16x8 a0 = *(const s16x8*)(smb + ra);
            s16x8 a1 = *(const s16x8*)(smb + (ra ^ 256));
            acc[dy][0] = __builtin_amdgcn_mfma_f32_16x16x32_bf16(a0, bfrag, acc[dy][0], 0, 0, 0);
            acc[dy][1] = __builtin_amdgcn_mfma_f32_16x16x32_bf16(a1, bfrag, acc[dy][1], 0, 0, 0);
        }
        bfrag = bnext;
    }

    float recv[8][2][4];
    #pragma unroll
    for (int dy = 0; dy < 8; ++dy)
        #pragma unroll
        for (int h = 0; h < 2; ++h)
            #pragma unroll
            for (int i = 0; i < 4; ++i)
                recv[dy][h][i] = __shfl_xor(acc[dy][h][i], 8);

    if (r < 8) {
        #pragma unroll
        for (int h = 0; h < 2; ++h)
            *(f32x4*)&handoff[wave * 256 + r * 32 + h * 16 + g * 4] = *(f32x4*)recv[7][h];
    }
    __syncthreads();

    if (r < 8) {
        const int pw = (wave + 3) & 3;
        f32x4 prev[2];
        #pragma unroll
        for (int h = 0; h < 2; ++h)
            prev[h] = *(f32x4*)&handoff[pw * 256 + r * 32 + h * 16 + g * 4];

        float* ob = out + (((size_t)(b * 256 + r * 32 + j)) << 10) + (g << 2);
        #pragma unroll
        for (int dy = 0; dy < 8; ++dy) {
            #pragma unroll
            for (int h = 0; h < 2; ++h) {
                f32x4 t1 = (dy == 0) ? prev[h] : *(f32x4*)recv[dy - 1][h];
                f32x4 v  = acc[dy][h] + t1;
                *(f32x4*)(ob + (y0 + dy) * 32 + h * 16) = v;
            }
        }
    }
}

// ===========================================================================
// TIER 3: fp32 VALU fallback (no workspace needed).
// ===========================================================================
__global__ __launch_bounds__(256, 2) void fconv_fallback(
    const float* __restrict__ x,
    const float* __restrict__ wgt,
    float* __restrict__ out)
{
    __shared__ float sw[16 * KK * KK * 8];
    const int tid = threadIdx.x;
    for (int idx = tid; idx < 8 * 16 * KK * KK; idx += 256) {
        int n  = idx / (16 * KK * KK);
        int rm = idx - n * (16 * KK * KK);
        int dc = rm / (KK * KK);
        int r2 = rm - dc * (KK * KK);
        int ky = r2 / KK;
        int kx = r2 - ky * KK;
        sw[((dc * KK + kx) * KK + ky) * 8 + n] = wgt[idx];
    }
    __syncthreads();

    const int bid = blockIdx.x;
    const int b   = bid >> 6;
    const int j   = (bid >> 1) & 31;
    const int yh  = bid & 1;
    const int xw  = tid & 31;
    const int yg  = tid >> 5;
    const int y_base = yh * 16 + yg * 2;

    int rows[10];
    #pragma unroll
    for (int i = 0; i < 10; ++i)
        rows[i] = ((y_base + 24 + i) & 31) << 5;

    float acc[8][2];
    #pragma unroll
    for (int n = 0; n < 8; ++n) { acc[n][0] = 0.f; acc[n][1] = 0.f; }

    const int c0 = 4 * j;
    #pragma unroll 1
    for (int dc = 0; dc < 16; ++dc) {
        const int c_src = (c0 - dc) & 127;
        const float* bx = x + (((size_t)b * 128 + c_src) << 10);
        #pragma unroll 1
        for (int kx = 0; kx < KK; ++kx) {
            const int x_col = (xw - kx) & 31;
            float win[10];
            #pragma unroll
            for (int i = 0; i < 10; ++i)
                win[i] = bx[rows[i] + x_col];
            const float4* wp = (const float4*)&sw[((dc * KK + kx) * KK) * 8];
            #pragma unroll
            for (int ky = 0; ky < KK; ++ky) {
                float4 wA = wp[2 * ky];
                float4 wB = wp[2 * ky + 1];
                float x0 = win[8 - ky];
                float x1 = win[9 - ky];
                acc[0][0] += x0 * wA.x; acc[0][1] += x1 * wA.x;
                acc[1][0] += x0 * wA.y; acc[1][1] += x1 * wA.y;
                acc[2][0] += x0 * wA.z; acc[2][1] += x1 * wA.z;
                acc[3][0] += x0 * wA.w; acc[3][1] += x1 * wA.w;
                acc[4][0] += x0 * wB.x; acc[4][1] += x1 * wB.x;
                acc[5][0] += x0 * wB.y; acc[5][1] += x1 * wB.y;
                acc[6][0] += x0 * wB.z; acc[6][1] += x1 * wB.z;
                acc[7][0] += x0 * wB.w; acc[7][1] += x1 * wB.w;
            }
        }
    }
    #pragma unroll
    for (int n = 0; n < 8; ++n) {
        float* op = out + ((((size_t)b * 256) + n * 32 + j) << 10) + (y_base << 5) + xw;
        op[0]  = acc[n][0];
        op[32] = acc[n][1];
    }
}

extern "C" void kernel_launch(void* const* d_in, const int* in_sizes, int n_in,
                              void* d_out, int out_size, void* d_ws, size_t ws_size,
                              hipStream_t stream) {
    const float* x   = (const float*)d_in[0];
    const float* w   = (const float*)d_in[1];
    float*       out = (float*)d_out;

    const size_t BG32_BYTES = (size_t)108 * 64 * 8 * sizeof(unsigned short);  // 110592
    const size_t BG16_BYTES = (size_t)NCHUNK * 4 * 16 * 8 * sizeof(unsigned short);

    if (ws_size >= BG32_BYTES) {
        unsigned short* Bg = (unsigned short*)d_ws;
        prep_w32<<<216, 256, 0, stream>>>(w, Bg);
        fconv_mfma32<<<512, 512, 0, stream>>>(x, Bg, out);
    } else if (ws_size >= BG16_BYTES) {
        unsigned short* Bg = (unsigned short*)d_ws;
        prep_w<<<46, 256, 0, stream>>>(w, Bg);
        fconv_mfma<<<1024, 256, 0, stream>>>(x, Bg, out);
    } else {
        fconv_fallback<<<2048, 256, 0, stream>>>(x, w, out);
    }
}